// Round 2
// 279.338 us; speedup vs baseline: 1.0728x; 1.0728x over previous
//
#include <hip/hip_runtime.h>
#include <hip/hip_bf16.h>
#include <math.h>

#define HH 512
#define WW 512
#define BC 48
#define GW 544                    // padded width: 16 left + 512 + 16 right
#define GH 545                    // padded height: 16 top + 512 + 17 bottom
#define PST (GH * GW)             // plane stride in elements (296480)

// LDS staging geometry for k_corr_mfma (16-row chunks — round-5 validated)
#define ROWB 384                  // staged bytes per row (192 bf16 cols)
#define COPYSTRIDE 6208           // bytes between parity copies (16B aligned, bank-shifted)
#define BUFSTRIDE (2 * COPYSTRIDE)
#define LDSBYTES (2 * BUFSTRIDE)  // 24832

// prep tile LDS strides
#define SIMS 98                   // bf16 row stride for 96-col staged tile (+2 pad)
#define HSS 65                    // fp32 row stride for hs (64 + 1 pad -> conflict-free)

typedef __bf16 v8bf __attribute__((ext_vector_type(8)));
typedef float v16f __attribute__((ext_vector_type(16)));

// ---------------------------------------------------------------------------
// Template normalization: Tn = (t - mean)/||t - mean|| per (b,c), bf16 out.
// ---------------------------------------------------------------------------
__global__ __launch_bounds__(256) void k_template(const float* __restrict__ t,
                                                  __hip_bfloat16* __restrict__ tn)
{
    __shared__ float red[256];
    const int bc = blockIdx.x, tid = threadIdx.x;
    const float* tp = t + bc * 1024;
    float v0 = tp[tid], v1 = tp[tid + 256], v2 = tp[tid + 512], v3 = tp[tid + 768];
    red[tid] = v0 + v1 + v2 + v3;
    __syncthreads();
    for (int sft = 128; sft > 0; sft >>= 1) {
        if (tid < sft) red[tid] += red[tid + sft];
        __syncthreads();
    }
    float mean = red[0] * (1.0f / 1024.0f);
    __syncthreads();
    float c0 = v0 - mean, c1 = v1 - mean, c2 = v2 - mean, c3 = v3 - mean;
    red[tid] = c0 * c0 + c1 * c1 + c2 * c2 + c3 * c3;
    __syncthreads();
    for (int sft = 128; sft > 0; sft >>= 1) {
        if (tid < sft) red[tid] += red[tid + sft];
        __syncthreads();
    }
    float norm = sqrtf(red[0]);
    __hip_bfloat16* o = tn + bc * 1024;
    o[tid] = __float2bfloat16(c0 / norm);
    o[tid + 256] = __float2bfloat16(c1 / norm);
    o[tid + 512] = __float2bfloat16(c2 / norm);
    o[tid + 768] = __float2bfloat16(c3 / norm);
}

// ---------------------------------------------------------------------------
// K1: fused 32x32 local-mean centering.
// Round-7 rewrite: 64x64 tile (43 KB LDS -> 3 blocks/CU), horizontal window
// sums parallelized over all 256 threads (95 rows x 4 sixteen-col chunks),
// hs stride padded to 65 (conflict-free).
// ---------------------------------------------------------------------------
__global__ __launch_bounds__(256) void k_center2(const float* __restrict__ im,
                                                 __hip_bfloat16* __restrict__ T0)
{
    __shared__ __hip_bfloat16 sim[95 * SIMS];
    __shared__ float hs[95 * HSS];
    const int j0 = blockIdx.x * 64;
    const int i0 = blockIdx.y * 64;
    const int plane = blockIdx.z;
    const int tid = threadIdx.x;
    const size_t iplane = (size_t)plane * HH * WW;
    const size_t gplane = (size_t)plane * PST;

    // stage 95x96 halo tile (rows i0-15..i0+79, cols j0-16..j0+79), bf16
    for (int k = tid; k < 95 * 96; k += 256) {
        int r = k / 96, c = k - r * 96;
        int gi = i0 + r - 15, gj = j0 + c - 16;
        float v = (gi >= 0 && gi < HH && gj >= 0 && gj < WW)
                      ? im[iplane + (size_t)gi * WW + gj] : 0.f;
        sim[r * SIMS + c] = __float2bfloat16(v);
    }
    __syncthreads();

    // horizontal 32-wide window sums: hs[r][j] = sum sim[r][j+1..j+32]
    // parallel over 95 rows x 4 chunks of 16 output cols = 380 tasks
    for (int t = tid; t < 95 * 4; t += 256) {
        const int r = t >> 2;
        const int q = (t & 3) << 4;
        const __hip_bfloat16* sr = sim + r * SIMS + q;
        float s = 0.f;
#pragma unroll
        for (int c = 1; c <= 32; ++c) s += __bfloat162float(sr[c]);
        float* hr = hs + r * HSS + q;
        hr[0] = s;
#pragma unroll
        for (int j = 1; j < 16; ++j) {
            s += __bfloat162float(sr[j + 32]) - __bfloat162float(sr[j]);
            hr[j] = s;
        }
    }
    __syncthreads();

    // vertical 32-window running sum: 64 cols x 4 row-groups of 16 rows
    const int tc = tid & 63;
    const int lr0 = (tid >> 6) << 4;
    float run = 0.f;
#pragma unroll
    for (int d = 0; d < 32; ++d) run += hs[(lr0 + d) * HSS + tc];
    for (int rr = 0; rr < 16; ++rr) {
        const int lr = lr0 + rr;
        float imv = __bfloat162float(sim[(lr + 15) * SIMS + tc + 16]);
        float val = imv - run * (1.0f / 1024.0f);
        T0[gplane + (size_t)(16 + i0 + lr) * GW + 16 + j0 + tc] = __float2bfloat16(val);
        if (rr < 15) run += hs[(lr + 32) * HSS + tc] - hs[lr * HSS + tc];
    }

    // zero padding margins
    if (blockIdx.x == 0) {
        for (int k = tid; k < 64 * 16; k += 256) {
            int rr = k >> 4, x = k & 15;
            T0[gplane + (size_t)(16 + i0 + rr) * GW + x] = __float2bfloat16(0.f);
        }
    }
    if (blockIdx.x == 7) {
        for (int k = tid; k < 64 * 16; k += 256) {
            int rr = k >> 4, x = k & 15;
            T0[gplane + (size_t)(16 + i0 + rr) * GW + 528 + x] = __float2bfloat16(0.f);
        }
    }
    if (blockIdx.x == 0 && blockIdx.y == 0) {
        for (int k = tid; k < 16 * GW; k += 256)
            T0[gplane + k] = __float2bfloat16(0.f);
    }
    if (blockIdx.x == 0 && blockIdx.y == 7) {
        size_t b = gplane + (size_t)528 * GW;
        for (int k = tid; k < 17 * GW; k += 256)
            T0[b + k] = __float2bfloat16(0.f);
    }
}

// ---------------------------------------------------------------------------
// K2: fused energy normalization. Same round-7 structure as k_center2:
// 64x64 tile, parallel horizontal sum-of-squares, hs stride 65.
// ---------------------------------------------------------------------------
__global__ __launch_bounds__(256) void k_norm2(const __hip_bfloat16* __restrict__ T0,
                                               __hip_bfloat16* __restrict__ G0,
                                               __hip_bfloat16* __restrict__ G1)
{
    __shared__ __hip_bfloat16 sim[95 * SIMS];
    __shared__ float hs[95 * HSS];
    const int j0 = blockIdx.x * 64;
    const int i0 = blockIdx.y * 64;
    const int plane = blockIdx.z;
    const int tid = threadIdx.x;
    const size_t gplane = (size_t)plane * PST;

    for (int k = tid; k < 95 * 96; k += 256) {
        int r = k / 96, c = k - r * 96;
        sim[r * SIMS + c] = T0[gplane + (size_t)(i0 + 1 + r) * GW + j0 + c];
    }
    __syncthreads();

    // horizontal 32-wide window sums of squares
    for (int t = tid; t < 95 * 4; t += 256) {
        const int r = t >> 2;
        const int q = (t & 3) << 4;
        const __hip_bfloat16* sr = sim + r * SIMS + q;
        float s = 0.f;
#pragma unroll
        for (int c = 1; c <= 32; ++c) {
            float v = __bfloat162float(sr[c]);
            s += v * v;
        }
        float* hr = hs + r * HSS + q;
        hr[0] = s;
#pragma unroll
        for (int j = 1; j < 16; ++j) {
            float a = __bfloat162float(sr[j + 32]);
            float b = __bfloat162float(sr[j]);
            s += a * a - b * b;
            hr[j] = s;
        }
    }
    __syncthreads();

    const int tc = tid & 63;
    const int lr0 = (tid >> 6) << 4;
    float run = 0.f;
#pragma unroll
    for (int d = 0; d < 32; ++d) run += hs[(lr0 + d) * HSS + tc];
    for (int rr = 0; rr < 16; ++rr) {
        const int lr = lr0 + rr;
        float e = sqrtf(fmaxf(run, 0.f));
        float v = __bfloat162float(sim[(lr + 15) * SIMS + tc + 16]) / e;
        __hip_bfloat16 w = __float2bfloat16(v);
        size_t pr = gplane + (size_t)(16 + i0 + lr) * GW;
        G0[pr + 16 + j0 + tc] = w;
        G1[pr + 15 + j0 + tc] = w;
        if (rr < 15) run += hs[(lr + 32) * HSS + tc] - hs[lr * HSS + tc];
    }

    if (blockIdx.x == 0) {
        for (int k = tid; k < 64 * 16; k += 256) {
            int rr = k >> 4, x = k & 15;
            size_t pr = gplane + (size_t)(16 + i0 + rr) * GW;
            G0[pr + x] = __float2bfloat16(0.f);
            if (x < 15) G1[pr + x] = __float2bfloat16(0.f);
        }
    }
    if (blockIdx.x == 7) {
        for (int k = tid; k < 64 * 17; k += 256) {
            int rr = k / 17, x = k % 17;
            size_t pr = gplane + (size_t)(16 + i0 + rr) * GW;
            G1[pr + 527 + x] = __float2bfloat16(0.f);
            if (x > 0) G0[pr + 527 + x] = __float2bfloat16(0.f);
        }
    }
    if (blockIdx.x == 0 && blockIdx.y == 0) {
        for (int k = tid; k < 16 * GW; k += 256) {
            G0[gplane + k] = __float2bfloat16(0.f);
            G1[gplane + k] = __float2bfloat16(0.f);
        }
    }
    if (blockIdx.x == 0 && blockIdx.y == 7) {
        size_t b = gplane + (size_t)528 * GW;
        for (int k = tid; k < 17 * GW; k += 256) {
            G0[b + k] = __float2bfloat16(0.f);
            G1[b + k] = __float2bfloat16(0.f);
        }
    }
}

// ---------------------------------------------------------------------------
// Corr compute: rotating-accumulator scheme. C slot base b=(q&3)+8*(q>>2)+4h
// holds (at step start) out row i = r+15-b. MFMA C-chaining does the
// accumulate; after MFMA, slot b=31 (h1 lanes, q15) retires a complete row;
// rotation b->b+1: within-lane renames + 4 half-crossing shfl_xor + inject 0.
// ---------------------------------------------------------------------------
template <int PHASE>
__device__ __forceinline__ void compute_chunk(const unsigned int* __restrict__ Lr,
                                              v8bf a0, v8bf a1,
                                              float (&C)[16],
                                              int h, int Tbase, int i0,
                                              float* outp)
{
#pragma unroll
    for (int t = 0; t < 16; ++t) {
        const unsigned int* p = Lr + PHASE * (BUFSTRIDE / 4) + t * (ROWB / 4);
        union { unsigned int u[4]; v8bf v; } B0, B1;
        B0.u[0] = p[0];  B0.u[1] = p[1];  B0.u[2] = p[2];  B0.u[3] = p[3];
        B1.u[0] = p[8];  B1.u[1] = p[9];  B1.u[2] = p[10]; B1.u[3] = p[11];
        v16f c;
#pragma unroll
        for (int q = 0; q < 16; ++q) c[q] = C[q];
        c = __builtin_amdgcn_mfma_f32_32x32x16_bf16(a1, B1.v, c, 0, 0, 0);
        c = __builtin_amdgcn_mfma_f32_32x32x16_bf16(a0, B0.v, c, 0, 0, 0);
        const int T = Tbase + t;                 // wave-uniform
        if (T >= 31 && T <= 94) {                // live retires only
            if (h) {
                const int ret = i0 - 31 + T;
                outp[(size_t)ret * WW] = c[15];  // b31 = complete out row
            }
        }
        // rotate b -> b+1
        float t3  = __shfl_xor(c[3], 32);
        float t7  = __shfl_xor(c[7], 32);
        float t11 = __shfl_xor(c[11], 32);
        float t15 = __shfl_xor(c[15], 32);
        C[0]  = h ? t3  : 0.f;                   // b4 <- b3 | inject 0 at b0
        C[4]  = h ? t7  : t3;                    // b12<-b11 | b8 <- b7
        C[8]  = h ? t11 : t7;                    // b20<-b19 | b16<- b15
        C[12] = h ? t15 : t11;                   // b28<-b27 | b24<- b23
#pragma unroll
        for (int g = 0; g < 4; ++g)
#pragma unroll
            for (int k = 1; k < 4; ++k)
                C[4 * g + k] = c[4 * g + k - 1]; // within-lane renames
    }
}

// ---------------------------------------------------------------------------
// Correlation: MFMA rotating-accumulator + async LDS double buffer
// (round-5 validated staging: 16-row chunks, wave-split 12x1KB segments).
// Block: 4 waves, 128 output cols x 64 output rows, sweep 96 image rows.
// ---------------------------------------------------------------------------
__global__ __launch_bounds__(256) void k_corr_mfma(const __hip_bfloat16* __restrict__ G0,
                                                   const __hip_bfloat16* __restrict__ G1,
                                                   const __hip_bfloat16* __restrict__ Tn,
                                                   float* __restrict__ out)
{
    __shared__ __align__(16) char lds[LDSBYTES];
    const int tid = threadIdx.x;
    const int wid = tid >> 6;
    const int lane = tid & 63;
    const int n = lane & 31;
    const int h = lane >> 5;
    const int j0 = blockIdx.x * 128;
    const int j0w = j0 + wid * 32;
    const int i0 = blockIdx.y * 64;
    const int plane = blockIdx.z;

    // A-operand: Tn fragments (whole template in registers)
    const v8bf* tp = (const v8bf*)(Tn + (size_t)plane * 1024 + n * 32 + 8 * h);
    const v8bf a0 = tp[0];
    const v8bf a1 = tp[2];

    // Reader: parity copy + dword base within staged row
    const int c0 = j0w + n - 15 + 8 * h;
    const int sel = c0 & 1;
    const int dbase = (32 * wid + n + 1 + 8 * h - sel) >> 1;
    const unsigned int* Lr = (const unsigned int*)(lds + sel * COPYSTRIDE) + dbase;

    const __hip_bfloat16* g0p = G0 + (size_t)plane * PST + (size_t)(i0 + 1) * GW + j0;
    const __hip_bfloat16* g1p = G1 + (size_t)plane * PST + (size_t)(i0 + 1) * GW + j0;

    // Stager: this wave's 3 of the 12 segments (s = wid, wid+4, wid+8)
    const __hip_bfloat16* srcp[3];
    int ldso[3];
#pragma unroll
    for (int k = 0; k < 3; ++k) {
        int s = wid + 4 * k;
        int cp = (s >= 6) ? 1 : 0;
        int c2 = cp ? (s - 6) : s;
        int q = c2 * 1024 + lane * 16;
        int rl = q / ROWB;
        int cb = q - rl * ROWB;
        srcp[k] = (cp ? g1p : g0p) + rl * GW + (cb >> 1);
        ldso[k] = cp * COPYSTRIDE + c2 * 1024;
    }

    float C[16];
#pragma unroll
    for (int s = 0; s < 16; s++) C[s] = 0.f;

    float* outp = out + (size_t)plane * HH * WW + j0w + n;

    auto stage = [&](int R, int b) {
#pragma unroll
        for (int k = 0; k < 3; ++k) {
            __builtin_amdgcn_global_load_lds(
                (const __attribute__((address_space(1))) void*)(srcp[k] + (size_t)R * GW),
                (__attribute__((address_space(3))) void*)(lds + b * BUFSTRIDE + ldso[k]),
                16, 0, 0);
        }
    };

    stage(0, 0);
    stage(16, 1);
    __syncthreads();

    for (int k2 = 0; k2 < 3; ++k2) {
        compute_chunk<0>(Lr, a0, a1, C, h, 32 * k2, i0, outp);
        __syncthreads();
        if (k2 < 2) stage(32 * k2 + 32, 0);
        compute_chunk<1>(Lr, a0, a1, C, h, 32 * k2 + 16, i0, outp);
        __syncthreads();
        if (k2 < 2) stage(32 * k2 + 48, 1);
    }
}

// ---------------------------------------------------------------------------
// Orchestration.
//   d_out : T0 (un-normalized padded bf16 im_c) -> final output
//   d_ws  : G0, G1 (bf16 padded dual copies), Tn (bf16)  — ~57 MB
// ---------------------------------------------------------------------------
extern "C" void kernel_launch(void* const* d_in, const int* in_sizes, int n_in,
                              void* d_out, int out_size, void* d_ws, size_t ws_size,
                              hipStream_t stream)
{
    const float* im = (const float*)d_in[0];
    const float* tmpl = (const float*)d_in[1];
    float* outp = (float*)d_out;
    __hip_bfloat16* T0 = (__hip_bfloat16*)d_out;
    __hip_bfloat16* G0 = (__hip_bfloat16*)d_ws;
    __hip_bfloat16* G1 = G0 + (size_t)BC * PST;
    __hip_bfloat16* Tn = G1 + (size_t)BC * PST;

    k_template<<<48, 256, 0, stream>>>(tmpl, Tn);
    k_center2<<<dim3(8, 8, BC), 256, 0, stream>>>(im, T0);
    k_norm2<<<dim3(8, 8, BC), 256, 0, stream>>>(T0, G0, G1);
    k_corr_mfma<<<dim3(4, 8, BC), 256, 0, stream>>>(G0, G1, Tn, outp);
}

// Round 9
// 269.155 us; speedup vs baseline: 1.1134x; 1.0378x over previous
//
#include <hip/hip_runtime.h>
#include <hip/hip_bf16.h>
#include <math.h>

#define HH 512
#define WW 512
#define BC 48
#define GW 544                    // padded width: 16 left + 512 + 16 right
#define GH 545                    // padded height: 16 top + 512 + 17 bottom
#define PST (GH * GW)             // plane stride in elements (296480)

// LDS staging geometry for k_corr_mfma (16-row chunks — round-5 validated)
#define ROWB 384                  // staged bytes per row (192 bf16 cols)
#define COPYSTRIDE 6208           // bytes between parity copies (16B aligned, bank-shifted)
#define BUFSTRIDE (2 * COPYSTRIDE)
#define LDSBYTES (2 * BUFSTRIDE)  // 24832

// prep tile LDS strides (32-row tiles, 5 blocks/CU)
#define SIMS 98                   // bf16 row stride for 96-col staged tile (+2 pad)
#define HSS 65                    // fp32 row stride for hs (64 + 1 pad -> conflict-free)
#define PR 63                     // staged rows per prep tile (32 out + 31 halo)

typedef __bf16 v8bf __attribute__((ext_vector_type(8)));
typedef float v16f __attribute__((ext_vector_type(16)));

// ---------------------------------------------------------------------------
// Template normalization: Tn = (t - mean)/||t - mean|| per (b,c), bf16 out.
// ---------------------------------------------------------------------------
__global__ __launch_bounds__(256) void k_template(const float* __restrict__ t,
                                                  __hip_bfloat16* __restrict__ tn)
{
    __shared__ float red[256];
    const int bc = blockIdx.x, tid = threadIdx.x;
    const float* tp = t + bc * 1024;
    float v0 = tp[tid], v1 = tp[tid + 256], v2 = tp[tid + 512], v3 = tp[tid + 768];
    red[tid] = v0 + v1 + v2 + v3;
    __syncthreads();
    for (int sft = 128; sft > 0; sft >>= 1) {
        if (tid < sft) red[tid] += red[tid + sft];
        __syncthreads();
    }
    float mean = red[0] * (1.0f / 1024.0f);
    __syncthreads();
    float c0 = v0 - mean, c1 = v1 - mean, c2 = v2 - mean, c3 = v3 - mean;
    red[tid] = c0 * c0 + c1 * c1 + c2 * c2 + c3 * c3;
    __syncthreads();
    for (int sft = 128; sft > 0; sft >>= 1) {
        if (tid < sft) red[tid] += red[tid + sft];
        __syncthreads();
    }
    float norm = sqrtf(red[0]);
    __hip_bfloat16* o = tn + bc * 1024;
    o[tid] = __float2bfloat16(c0 / norm);
    o[tid + 256] = __float2bfloat16(c1 / norm);
    o[tid + 512] = __float2bfloat16(c2 / norm);
    o[tid + 768] = __float2bfloat16(c3 / norm);
}

// ---------------------------------------------------------------------------
// K1: fused 32x32 local-mean centering.
// 64x32 tile (29 KB LDS -> 5 blocks/CU), horizontal pass = 252 tasks over
// 256 threads (single balanced round), hs stride 65.
// ---------------------------------------------------------------------------
__global__ __launch_bounds__(256) void k_center2(const float* __restrict__ im,
                                                 __hip_bfloat16* __restrict__ T0)
{
    __shared__ float hs[PR * HSS];
    __shared__ __hip_bfloat16 sim[PR * SIMS];
    const int j0 = blockIdx.x * 64;
    const int i0 = blockIdx.y * 32;
    const int plane = blockIdx.z;
    const int tid = threadIdx.x;
    const size_t iplane = (size_t)plane * HH * WW;
    const size_t gplane = (size_t)plane * PST;

    // stage 63x96 halo tile (rows i0-15..i0+47, cols j0-16..j0+79), bf16
    for (int k = tid; k < PR * 96; k += 256) {
        int r = k / 96, c = k - r * 96;
        int gi = i0 + r - 15, gj = j0 + c - 16;
        float v = (gi >= 0 && gi < HH && gj >= 0 && gj < WW)
                      ? im[iplane + (size_t)gi * WW + gj] : 0.f;
        sim[r * SIMS + c] = __float2bfloat16(v);
    }
    __syncthreads();

    // horizontal 32-wide window sums: hs[r][j] = sum sim[r][j+1..j+32]
    // 63 rows x 4 chunks of 16 output cols = 252 tasks, one round
    if (tid < PR * 4) {
        const int r = tid >> 2;
        const int q = (tid & 3) << 4;
        const __hip_bfloat16* sr = sim + r * SIMS + q;
        float s = 0.f;
#pragma unroll
        for (int c = 1; c <= 32; ++c) s += __bfloat162float(sr[c]);
        float* hr = hs + r * HSS + q;
        hr[0] = s;
#pragma unroll
        for (int j = 1; j < 16; ++j) {
            s += __bfloat162float(sr[j + 32]) - __bfloat162float(sr[j]);
            hr[j] = s;
        }
    }
    __syncthreads();

    // vertical 32-window running sum: 64 cols x 4 row-groups of 8 rows
    const int tc = tid & 63;
    const int lr0 = (tid >> 6) << 3;
    float run = 0.f;
#pragma unroll
    for (int d = 0; d < 32; ++d) run += hs[(lr0 + d) * HSS + tc];
    for (int rr = 0; rr < 8; ++rr) {
        const int lr = lr0 + rr;
        float imv = __bfloat162float(sim[(lr + 15) * SIMS + tc + 16]);
        float val = imv - run * (1.0f / 1024.0f);
        T0[gplane + (size_t)(16 + i0 + lr) * GW + 16 + j0 + tc] = __float2bfloat16(val);
        if (rr < 7) run += hs[(lr + 32) * HSS + tc] - hs[lr * HSS + tc];
    }

    // zero padding margins
    if (blockIdx.x == 0) {
        for (int k = tid; k < 32 * 16; k += 256) {
            int rr = k >> 4, x = k & 15;
            T0[gplane + (size_t)(16 + i0 + rr) * GW + x] = __float2bfloat16(0.f);
        }
    }
    if (blockIdx.x == 7) {
        for (int k = tid; k < 32 * 16; k += 256) {
            int rr = k >> 4, x = k & 15;
            T0[gplane + (size_t)(16 + i0 + rr) * GW + 528 + x] = __float2bfloat16(0.f);
        }
    }
    if (blockIdx.x == 0 && blockIdx.y == 0) {
        for (int k = tid; k < 16 * GW; k += 256)
            T0[gplane + k] = __float2bfloat16(0.f);
    }
    if (blockIdx.x == 0 && blockIdx.y == 15) {
        size_t b = gplane + (size_t)528 * GW;
        for (int k = tid; k < 17 * GW; k += 256)
            T0[b + k] = __float2bfloat16(0.f);
    }
}

// ---------------------------------------------------------------------------
// K2: fused energy normalization. Same structure as k_center2.
// ---------------------------------------------------------------------------
__global__ __launch_bounds__(256) void k_norm2(const __hip_bfloat16* __restrict__ T0,
                                               __hip_bfloat16* __restrict__ G0,
                                               __hip_bfloat16* __restrict__ G1)
{
    __shared__ float hs[PR * HSS];
    __shared__ __hip_bfloat16 sim[PR * SIMS];
    const int j0 = blockIdx.x * 64;
    const int i0 = blockIdx.y * 32;
    const int plane = blockIdx.z;
    const int tid = threadIdx.x;
    const size_t gplane = (size_t)plane * PST;

    for (int k = tid; k < PR * 96; k += 256) {
        int r = k / 96, c = k - r * 96;
        sim[r * SIMS + c] = T0[gplane + (size_t)(i0 + 1 + r) * GW + j0 + c];
    }
    __syncthreads();

    // horizontal 32-wide window sums of squares
    if (tid < PR * 4) {
        const int r = tid >> 2;
        const int q = (tid & 3) << 4;
        const __hip_bfloat16* sr = sim + r * SIMS + q;
        float s = 0.f;
#pragma unroll
        for (int c = 1; c <= 32; ++c) {
            float v = __bfloat162float(sr[c]);
            s += v * v;
        }
        float* hr = hs + r * HSS + q;
        hr[0] = s;
#pragma unroll
        for (int j = 1; j < 16; ++j) {
            float a = __bfloat162float(sr[j + 32]);
            float b = __bfloat162float(sr[j]);
            s += a * a - b * b;
            hr[j] = s;
        }
    }
    __syncthreads();

    const int tc = tid & 63;
    const int lr0 = (tid >> 6) << 3;
    float run = 0.f;
#pragma unroll
    for (int d = 0; d < 32; ++d) run += hs[(lr0 + d) * HSS + tc];
    for (int rr = 0; rr < 8; ++rr) {
        const int lr = lr0 + rr;
        float e = sqrtf(fmaxf(run, 0.f));
        float v = __bfloat162float(sim[(lr + 15) * SIMS + tc + 16]) / e;
        __hip_bfloat16 w = __float2bfloat16(v);
        size_t pr = gplane + (size_t)(16 + i0 + lr) * GW;
        G0[pr + 16 + j0 + tc] = w;
        G1[pr + 15 + j0 + tc] = w;
        if (rr < 7) run += hs[(lr + 32) * HSS + tc] - hs[lr * HSS + tc];
    }

    if (blockIdx.x == 0) {
        for (int k = tid; k < 32 * 16; k += 256) {
            int rr = k >> 4, x = k & 15;
            size_t pr = gplane + (size_t)(16 + i0 + rr) * GW;
            G0[pr + x] = __float2bfloat16(0.f);
            if (x < 15) G1[pr + x] = __float2bfloat16(0.f);
        }
    }
    if (blockIdx.x == 7) {
        for (int k = tid; k < 32 * 17; k += 256) {
            int rr = k / 17, x = k % 17;
            size_t pr = gplane + (size_t)(16 + i0 + rr) * GW;
            G1[pr + 527 + x] = __float2bfloat16(0.f);
            if (x > 0) G0[pr + 527 + x] = __float2bfloat16(0.f);
        }
    }
    if (blockIdx.x == 0 && blockIdx.y == 0) {
        for (int k = tid; k < 16 * GW; k += 256) {
            G0[gplane + k] = __float2bfloat16(0.f);
            G1[gplane + k] = __float2bfloat16(0.f);
        }
    }
    if (blockIdx.x == 0 && blockIdx.y == 15) {
        size_t b = gplane + (size_t)528 * GW;
        for (int k = tid; k < 17 * GW; k += 256) {
            G0[b + k] = __float2bfloat16(0.f);
            G1[b + k] = __float2bfloat16(0.f);
        }
    }
}

// ---------------------------------------------------------------------------
// Corr compute: rotating-accumulator scheme — KNOWN-GOOD round-2 version
// (half-crossings via __shfl_xor; permlane variant failed twice, bisecting).
// C slot base b=(q&3)+8*(q>>2)+4h holds (at step start) out row i = r+15-b.
// MFMA C-chaining accumulates; after MFMA, slot b=31 (h1, q15) retires a
// complete row; rotation b->b+1: within-lane renames + 4 shfl_xor + inject 0.
// ---------------------------------------------------------------------------
template <int PHASE>
__device__ __forceinline__ void compute_chunk(const unsigned int* __restrict__ Lr,
                                              v8bf a0, v8bf a1,
                                              float (&C)[16],
                                              int h, int Tbase, int i0,
                                              float* outp)
{
#pragma unroll
    for (int t = 0; t < 16; ++t) {
        const unsigned int* p = Lr + PHASE * (BUFSTRIDE / 4) + t * (ROWB / 4);
        union { unsigned int u[4]; v8bf v; } B0, B1;
        B0.u[0] = p[0];  B0.u[1] = p[1];  B0.u[2] = p[2];  B0.u[3] = p[3];
        B1.u[0] = p[8];  B1.u[1] = p[9];  B1.u[2] = p[10]; B1.u[3] = p[11];
        v16f c;
#pragma unroll
        for (int q = 0; q < 16; ++q) c[q] = C[q];
        c = __builtin_amdgcn_mfma_f32_32x32x16_bf16(a1, B1.v, c, 0, 0, 0);
        c = __builtin_amdgcn_mfma_f32_32x32x16_bf16(a0, B0.v, c, 0, 0, 0);
        const int T = Tbase + t;                 // wave-uniform
        if (T >= 31 && T <= 94) {                // live retires only
            if (h) {
                const int ret = i0 - 31 + T;
                outp[(size_t)ret * WW] = c[15];  // b31 = complete out row
            }
        }
        // rotate b -> b+1
        float t3  = __shfl_xor(c[3], 32);
        float t7  = __shfl_xor(c[7], 32);
        float t11 = __shfl_xor(c[11], 32);
        float t15 = __shfl_xor(c[15], 32);
        C[0]  = h ? t3  : 0.f;                   // b4 <- b3 | inject 0 at b0
        C[4]  = h ? t7  : t3;                    // b12<-b11 | b8 <- b7
        C[8]  = h ? t11 : t7;                    // b20<-b19 | b16<- b15
        C[12] = h ? t15 : t11;                   // b28<-b27 | b24<- b23
#pragma unroll
        for (int g = 0; g < 4; ++g)
#pragma unroll
            for (int k = 1; k < 4; ++k)
                C[4 * g + k] = c[4 * g + k - 1]; // within-lane renames
    }
}

// ---------------------------------------------------------------------------
// Correlation: MFMA rotating-accumulator + async LDS double buffer
// (round-5 validated staging: 16-row chunks, wave-split 12x1KB segments).
// Block: 4 waves, 128 output cols x 64 output rows, sweep 96 image rows.
// ---------------------------------------------------------------------------
__global__ __launch_bounds__(256) void k_corr_mfma(const __hip_bfloat16* __restrict__ G0,
                                                   const __hip_bfloat16* __restrict__ G1,
                                                   const __hip_bfloat16* __restrict__ Tn,
                                                   float* __restrict__ out)
{
    __shared__ __align__(16) char lds[LDSBYTES];
    const int tid = threadIdx.x;
    const int wid = tid >> 6;
    const int lane = tid & 63;
    const int n = lane & 31;
    const int h = lane >> 5;
    const int j0 = blockIdx.x * 128;
    const int j0w = j0 + wid * 32;
    const int i0 = blockIdx.y * 64;
    const int plane = blockIdx.z;

    // A-operand: Tn fragments (whole template in registers)
    const v8bf* tp = (const v8bf*)(Tn + (size_t)plane * 1024 + n * 32 + 8 * h);
    const v8bf a0 = tp[0];
    const v8bf a1 = tp[2];

    // Reader: parity copy + dword base within staged row
    const int c0 = j0w + n - 15 + 8 * h;
    const int sel = c0 & 1;
    const int dbase = (32 * wid + n + 1 + 8 * h - sel) >> 1;
    const unsigned int* Lr = (const unsigned int*)(lds + sel * COPYSTRIDE) + dbase;

    const __hip_bfloat16* g0p = G0 + (size_t)plane * PST + (size_t)(i0 + 1) * GW + j0;
    const __hip_bfloat16* g1p = G1 + (size_t)plane * PST + (size_t)(i0 + 1) * GW + j0;

    // Stager: this wave's 3 of the 12 segments (s = wid, wid+4, wid+8)
    const __hip_bfloat16* srcp[3];
    int ldso[3];
#pragma unroll
    for (int k = 0; k < 3; ++k) {
        int s = wid + 4 * k;
        int cp = (s >= 6) ? 1 : 0;
        int c2 = cp ? (s - 6) : s;
        int q = c2 * 1024 + lane * 16;
        int rl = q / ROWB;
        int cb = q - rl * ROWB;
        srcp[k] = (cp ? g1p : g0p) + rl * GW + (cb >> 1);
        ldso[k] = cp * COPYSTRIDE + c2 * 1024;
    }

    float C[16];
#pragma unroll
    for (int s = 0; s < 16; s++) C[s] = 0.f;

    float* outp = out + (size_t)plane * HH * WW + j0w + n;

    auto stage = [&](int R, int b) {
#pragma unroll
        for (int k = 0; k < 3; ++k) {
            __builtin_amdgcn_global_load_lds(
                (const __attribute__((address_space(1))) void*)(srcp[k] + (size_t)R * GW),
                (__attribute__((address_space(3))) void*)(lds + b * BUFSTRIDE + ldso[k]),
                16, 0, 0);
        }
    };

    stage(0, 0);
    stage(16, 1);
    __syncthreads();

    for (int k2 = 0; k2 < 3; ++k2) {
        compute_chunk<0>(Lr, a0, a1, C, h, 32 * k2, i0, outp);
        __syncthreads();
        if (k2 < 2) stage(32 * k2 + 32, 0);
        compute_chunk<1>(Lr, a0, a1, C, h, 32 * k2 + 16, i0, outp);
        __syncthreads();
        if (k2 < 2) stage(32 * k2 + 48, 1);
    }
}

// ---------------------------------------------------------------------------
// Orchestration.
//   d_out : T0 (un-normalized padded bf16 im_c) -> final output
//   d_ws  : G0, G1 (bf16 padded dual copies), Tn (bf16)  — ~57 MB
// ---------------------------------------------------------------------------
extern "C" void kernel_launch(void* const* d_in, const int* in_sizes, int n_in,
                              void* d_out, int out_size, void* d_ws, size_t ws_size,
                              hipStream_t stream)
{
    const float* im = (const float*)d_in[0];
    const float* tmpl = (const float*)d_in[1];
    float* outp = (float*)d_out;
    __hip_bfloat16* T0 = (__hip_bfloat16*)d_out;
    __hip_bfloat16* G0 = (__hip_bfloat16*)d_ws;
    __hip_bfloat16* G1 = G0 + (size_t)BC * PST;
    __hip_bfloat16* Tn = G1 + (size_t)BC * PST;

    k_template<<<48, 256, 0, stream>>>(tmpl, Tn);
    k_center2<<<dim3(8, 16, BC), 256, 0, stream>>>(im, T0);
    k_norm2<<<dim3(8, 16, BC), 256, 0, stream>>>(T0, G0, G1);
    k_corr_mfma<<<dim3(4, 8, BC), 256, 0, stream>>>(G0, G1, Tn, outp);
}

// Round 13
// 250.904 us; speedup vs baseline: 1.1944x; 1.0727x over previous
//
#include <hip/hip_runtime.h>
#include <hip/hip_bf16.h>
#include <math.h>

#define HH 512
#define WW 512
#define BC 48
#define GW 544                    // padded width: 16 left + 512 + 16 right
#define GH 545                    // padded height: 16 top + 512 + 17 bottom
#define PST (GH * GW)             // plane stride in elements (296480)

// LDS staging geometry for k_corr_mfma (16-row chunks — round-5 validated)
#define ROWB 384                  // staged bytes per row (192 bf16 cols)
#define COPYSTRIDE 6208           // bytes between parity copies (16B aligned, bank-shifted)
#define BUFSTRIDE (2 * COPYSTRIDE)
#define LDSBYTES (2 * BUFSTRIDE)  // 24832

// prep tile LDS strides (32-row tiles, 5 blocks/CU)
#define SIMS 100                  // bf16 row stride, multiple of 4 for ushort4 stores
#define HSS 65                    // fp32 row stride for hs (64 + 1 pad -> conflict-free)
#define PR 63                     // staged rows per prep tile (32 out + 31 halo)

typedef __bf16 v8bf __attribute__((ext_vector_type(8)));
typedef float v16f __attribute__((ext_vector_type(16)));

// ---------------------------------------------------------------------------
// Template normalization: Tn = (t - mean)/||t - mean|| per (b,c), bf16 out.
// ---------------------------------------------------------------------------
__global__ __launch_bounds__(256) void k_template(const float* __restrict__ t,
                                                  __hip_bfloat16* __restrict__ tn)
{
    __shared__ float red[256];
    const int bc = blockIdx.x, tid = threadIdx.x;
    const float* tp = t + bc * 1024;
    float v0 = tp[tid], v1 = tp[tid + 256], v2 = tp[tid + 512], v3 = tp[tid + 768];
    red[tid] = v0 + v1 + v2 + v3;
    __syncthreads();
    for (int sft = 128; sft > 0; sft >>= 1) {
        if (tid < sft) red[tid] += red[tid + sft];
        __syncthreads();
    }
    float mean = red[0] * (1.0f / 1024.0f);
    __syncthreads();
    float c0 = v0 - mean, c1 = v1 - mean, c2 = v2 - mean, c3 = v3 - mean;
    red[tid] = c0 * c0 + c1 * c1 + c2 * c2 + c3 * c3;
    __syncthreads();
    for (int sft = 128; sft > 0; sft >>= 1) {
        if (tid < sft) red[tid] += red[tid + sft];
        __syncthreads();
    }
    float norm = sqrtf(red[0]);
    __hip_bfloat16* o = tn + bc * 1024;
    o[tid] = __float2bfloat16(c0 / norm);
    o[tid + 256] = __float2bfloat16(c1 / norm);
    o[tid + 512] = __float2bfloat16(c2 / norm);
    o[tid + 768] = __float2bfloat16(c3 / norm);
}

// ---------------------------------------------------------------------------
// K1: fused 32x32 local-mean centering. 64x32 tile, 5 blocks/CU.
// Round-10: interior blocks stage via float4 loads + ushort4 LDS stores
// (24 -> 6 rounds); edge blocks keep the scalar bounds-checked path.
// ---------------------------------------------------------------------------
__global__ __launch_bounds__(256) void k_center2(const float* __restrict__ im,
                                                 __hip_bfloat16* __restrict__ T0)
{
    __shared__ float hs[PR * HSS];
    __shared__ __hip_bfloat16 sim[PR * SIMS];
    const int j0 = blockIdx.x * 64;
    const int i0 = blockIdx.y * 32;
    const int plane = blockIdx.z;
    const int tid = threadIdx.x;
    const size_t iplane = (size_t)plane * HH * WW;
    const size_t gplane = (size_t)plane * PST;

    // stage 63x96 halo tile (rows i0-15..i0+47, cols j0-16..j0+79), bf16
    const bool interior = (blockIdx.x >= 1 && blockIdx.x <= 6 &&
                           blockIdx.y >= 1 && blockIdx.y <= 14);
    if (interior) {
        for (int k = tid; k < PR * 24; k += 256) {
            int r = k / 24, c4 = (k - r * 24) * 4;
            const float4 v = *reinterpret_cast<const float4*>(
                &im[iplane + (size_t)(i0 + r - 15) * WW + (j0 - 16 + c4)]);
            __hip_bfloat16 b0 = __float2bfloat16(v.x), b1 = __float2bfloat16(v.y);
            __hip_bfloat16 b2 = __float2bfloat16(v.z), b3 = __float2bfloat16(v.w);
            ushort4 u;
            u.x = *(unsigned short*)&b0; u.y = *(unsigned short*)&b1;
            u.z = *(unsigned short*)&b2; u.w = *(unsigned short*)&b3;
            *reinterpret_cast<ushort4*>(&sim[r * SIMS + c4]) = u;
        }
    } else {
        for (int k = tid; k < PR * 96; k += 256) {
            int r = k / 96, c = k - r * 96;
            int gi = i0 + r - 15, gj = j0 + c - 16;
            float v = (gi >= 0 && gi < HH && gj >= 0 && gj < WW)
                          ? im[iplane + (size_t)gi * WW + gj] : 0.f;
            sim[r * SIMS + c] = __float2bfloat16(v);
        }
    }
    __syncthreads();

    // horizontal 32-wide window sums: hs[r][j] = sum sim[r][j+1..j+32]
    if (tid < PR * 4) {
        const int r = tid >> 2;
        const int q = (tid & 3) << 4;
        const __hip_bfloat16* sr = sim + r * SIMS + q;
        float s = 0.f;
#pragma unroll
        for (int c = 1; c <= 32; ++c) s += __bfloat162float(sr[c]);
        float* hr = hs + r * HSS + q;
        hr[0] = s;
#pragma unroll
        for (int j = 1; j < 16; ++j) {
            s += __bfloat162float(sr[j + 32]) - __bfloat162float(sr[j]);
            hr[j] = s;
        }
    }
    __syncthreads();

    // vertical 32-window running sum: 64 cols x 4 row-groups of 8 rows
    const int tc = tid & 63;
    const int lr0 = (tid >> 6) << 3;
    float run = 0.f;
#pragma unroll
    for (int d = 0; d < 32; ++d) run += hs[(lr0 + d) * HSS + tc];
    for (int rr = 0; rr < 8; ++rr) {
        const int lr = lr0 + rr;
        float imv = __bfloat162float(sim[(lr + 15) * SIMS + tc + 16]);
        float val = imv - run * (1.0f / 1024.0f);
        T0[gplane + (size_t)(16 + i0 + lr) * GW + 16 + j0 + tc] = __float2bfloat16(val);
        if (rr < 7) run += hs[(lr + 32) * HSS + tc] - hs[lr * HSS + tc];
    }

    // zero padding margins
    if (blockIdx.x == 0) {
        for (int k = tid; k < 32 * 16; k += 256) {
            int rr = k >> 4, x = k & 15;
            T0[gplane + (size_t)(16 + i0 + rr) * GW + x] = __float2bfloat16(0.f);
        }
    }
    if (blockIdx.x == 7) {
        for (int k = tid; k < 32 * 16; k += 256) {
            int rr = k >> 4, x = k & 15;
            T0[gplane + (size_t)(16 + i0 + rr) * GW + 528 + x] = __float2bfloat16(0.f);
        }
    }
    if (blockIdx.x == 0 && blockIdx.y == 0) {
        for (int k = tid; k < 16 * GW; k += 256)
            T0[gplane + k] = __float2bfloat16(0.f);
    }
    if (blockIdx.x == 0 && blockIdx.y == 15) {
        size_t b = gplane + (size_t)528 * GW;
        for (int k = tid; k < 17 * GW; k += 256)
            T0[b + k] = __float2bfloat16(0.f);
    }
}

// ---------------------------------------------------------------------------
// K2: fused energy normalization. Staging reads the padded T0 plane — always
// in-bounds and 8B-aligned, so unconditional ushort4 vector loads.
// ---------------------------------------------------------------------------
__global__ __launch_bounds__(256) void k_norm2(const __hip_bfloat16* __restrict__ T0,
                                               __hip_bfloat16* __restrict__ G0,
                                               __hip_bfloat16* __restrict__ G1)
{
    __shared__ float hs[PR * HSS];
    __shared__ __hip_bfloat16 sim[PR * SIMS];
    const int j0 = blockIdx.x * 64;
    const int i0 = blockIdx.y * 32;
    const int plane = blockIdx.z;
    const int tid = threadIdx.x;
    const size_t gplane = (size_t)plane * PST;

    for (int k = tid; k < PR * 24; k += 256) {
        int r = k / 24, c4 = (k - r * 24) * 4;
        ushort4 u = *reinterpret_cast<const ushort4*>(
            &T0[gplane + (size_t)(i0 + 1 + r) * GW + j0 + c4]);
        *reinterpret_cast<ushort4*>(&sim[r * SIMS + c4]) = u;
    }
    __syncthreads();

    // horizontal 32-wide window sums of squares
    if (tid < PR * 4) {
        const int r = tid >> 2;
        const int q = (tid & 3) << 4;
        const __hip_bfloat16* sr = sim + r * SIMS + q;
        float s = 0.f;
#pragma unroll
        for (int c = 1; c <= 32; ++c) {
            float v = __bfloat162float(sr[c]);
            s += v * v;
        }
        float* hr = hs + r * HSS + q;
        hr[0] = s;
#pragma unroll
        for (int j = 1; j < 16; ++j) {
            float a = __bfloat162float(sr[j + 32]);
            float b = __bfloat162float(sr[j]);
            s += a * a - b * b;
            hr[j] = s;
        }
    }
    __syncthreads();

    const int tc = tid & 63;
    const int lr0 = (tid >> 6) << 3;
    float run = 0.f;
#pragma unroll
    for (int d = 0; d < 32; ++d) run += hs[(lr0 + d) * HSS + tc];
    for (int rr = 0; rr < 8; ++rr) {
        const int lr = lr0 + rr;
        float e = sqrtf(fmaxf(run, 0.f));
        float v = __bfloat162float(sim[(lr + 15) * SIMS + tc + 16]) / e;
        __hip_bfloat16 w = __float2bfloat16(v);
        size_t pr = gplane + (size_t)(16 + i0 + lr) * GW;
        G0[pr + 16 + j0 + tc] = w;
        G1[pr + 15 + j0 + tc] = w;
        if (rr < 7) run += hs[(lr + 32) * HSS + tc] - hs[lr * HSS + tc];
    }

    if (blockIdx.x == 0) {
        for (int k = tid; k < 32 * 16; k += 256) {
            int rr = k >> 4, x = k & 15;
            size_t pr = gplane + (size_t)(16 + i0 + rr) * GW;
            G0[pr + x] = __float2bfloat16(0.f);
            if (x < 15) G1[pr + x] = __float2bfloat16(0.f);
        }
    }
    if (blockIdx.x == 7) {
        for (int k = tid; k < 32 * 17; k += 256) {
            int rr = k / 17, x = k % 17;
            size_t pr = gplane + (size_t)(16 + i0 + rr) * GW;
            G1[pr + 527 + x] = __float2bfloat16(0.f);
            if (x > 0) G0[pr + 527 + x] = __float2bfloat16(0.f);
        }
    }
    if (blockIdx.x == 0 && blockIdx.y == 0) {
        for (int k = tid; k < 16 * GW; k += 256) {
            G0[gplane + k] = __float2bfloat16(0.f);
            G1[gplane + k] = __float2bfloat16(0.f);
        }
    }
    if (blockIdx.x == 0 && blockIdx.y == 15) {
        size_t b = gplane + (size_t)528 * GW;
        for (int k = tid; k < 17 * GW; k += 256) {
            G0[b + k] = __float2bfloat16(0.f);
            G1[b + k] = __float2bfloat16(0.f);
        }
    }
}

// ---------------------------------------------------------------------------
// Corr compute: rotating-accumulator (known-good shfl_xor version).
// Round-10: retire window extended for 128-row tiles (T in [31,158]).
// ---------------------------------------------------------------------------
template <int PHASE>
__device__ __forceinline__ void compute_chunk(const unsigned int* __restrict__ Lr,
                                              v8bf a0, v8bf a1,
                                              float (&C)[16],
                                              int h, int Tbase, int i0,
                                              float* outp)
{
#pragma unroll
    for (int t = 0; t < 16; ++t) {
        const unsigned int* p = Lr + PHASE * (BUFSTRIDE / 4) + t * (ROWB / 4);
        union { unsigned int u[4]; v8bf v; } B0, B1;
        B0.u[0] = p[0];  B0.u[1] = p[1];  B0.u[2] = p[2];  B0.u[3] = p[3];
        B1.u[0] = p[8];  B1.u[1] = p[9];  B1.u[2] = p[10]; B1.u[3] = p[11];
        v16f c;
#pragma unroll
        for (int q = 0; q < 16; ++q) c[q] = C[q];
        c = __builtin_amdgcn_mfma_f32_32x32x16_bf16(a1, B1.v, c, 0, 0, 0);
        c = __builtin_amdgcn_mfma_f32_32x32x16_bf16(a0, B0.v, c, 0, 0, 0);
        const int T = Tbase + t;                 // wave-uniform
        if (T >= 31 && T <= 158) {               // live retires only (128 rows)
            if (h) {
                const int ret = i0 - 31 + T;
                outp[(size_t)ret * WW] = c[15];  // b31 = complete out row
            }
        }
        // rotate b -> b+1
        float t3  = __shfl_xor(c[3], 32);
        float t7  = __shfl_xor(c[7], 32);
        float t11 = __shfl_xor(c[11], 32);
        float t15 = __shfl_xor(c[15], 32);
        C[0]  = h ? t3  : 0.f;                   // b4 <- b3 | inject 0 at b0
        C[4]  = h ? t7  : t3;                    // b12<-b11 | b8 <- b7
        C[8]  = h ? t11 : t7;                    // b20<-b19 | b16<- b15
        C[12] = h ? t15 : t11;                   // b28<-b27 | b24<- b23
#pragma unroll
        for (int g = 0; g < 4; ++g)
#pragma unroll
            for (int k = 1; k < 4; ++k)
                C[4 * g + k] = c[4 * g + k - 1]; // within-lane renames
    }
}

// ---------------------------------------------------------------------------
// Correlation: MFMA rotating-accumulator + async LDS double buffer.
// Round-10: 128-row output tiles (sweep 160 rows, 10 chunks) — ramp-in waste
// drops from 33% to 20% of steps; grid y 8 -> 4. Last tile reads padded rows
// up to 544 = GH-1 (exact fit). LDS/VGPR unchanged.
// ---------------------------------------------------------------------------
__global__ __launch_bounds__(256) void k_corr_mfma(const __hip_bfloat16* __restrict__ G0,
                                                   const __hip_bfloat16* __restrict__ G1,
                                                   const __hip_bfloat16* __restrict__ Tn,
                                                   float* __restrict__ out)
{
    __shared__ __align__(16) char lds[LDSBYTES];
    const int tid = threadIdx.x;
    const int wid = tid >> 6;
    const int lane = tid & 63;
    const int n = lane & 31;
    const int h = lane >> 5;
    const int j0 = blockIdx.x * 128;
    const int j0w = j0 + wid * 32;
    const int i0 = blockIdx.y * 128;
    const int plane = blockIdx.z;

    // A-operand: Tn fragments (whole template in registers)
    const v8bf* tp = (const v8bf*)(Tn + (size_t)plane * 1024 + n * 32 + 8 * h);
    const v8bf a0 = tp[0];
    const v8bf a1 = tp[2];

    // Reader: parity copy + dword base within staged row
    const int c0 = j0w + n - 15 + 8 * h;
    const int sel = c0 & 1;
    const int dbase = (32 * wid + n + 1 + 8 * h - sel) >> 1;
    const unsigned int* Lr = (const unsigned int*)(lds + sel * COPYSTRIDE) + dbase;

    const __hip_bfloat16* g0p = G0 + (size_t)plane * PST + (size_t)(i0 + 1) * GW + j0;
    const __hip_bfloat16* g1p = G1 + (size_t)plane * PST + (size_t)(i0 + 1) * GW + j0;

    // Stager: this wave's 3 of the 12 segments (s = wid, wid+4, wid+8)
    const __hip_bfloat16* srcp[3];
    int ldso[3];
#pragma unroll
    for (int k = 0; k < 3; ++k) {
        int s = wid + 4 * k;
        int cp = (s >= 6) ? 1 : 0;
        int c2 = cp ? (s - 6) : s;
        int q = c2 * 1024 + lane * 16;
        int rl = q / ROWB;
        int cb = q - rl * ROWB;
        srcp[k] = (cp ? g1p : g0p) + rl * GW + (cb >> 1);
        ldso[k] = cp * COPYSTRIDE + c2 * 1024;
    }

    float C[16];
#pragma unroll
    for (int s = 0; s < 16; s++) C[s] = 0.f;

    float* outp = out + (size_t)plane * HH * WW + j0w + n;

    auto stage = [&](int R, int b) {
#pragma unroll
        for (int k = 0; k < 3; ++k) {
            __builtin_amdgcn_global_load_lds(
                (const __attribute__((address_space(1))) void*)(srcp[k] + (size_t)R * GW),
                (__attribute__((address_space(3))) void*)(lds + b * BUFSTRIDE + ldso[k]),
                16, 0, 0);
        }
    };

    stage(0, 0);
    stage(16, 1);
    __syncthreads();

    for (int k2 = 0; k2 < 5; ++k2) {
        compute_chunk<0>(Lr, a0, a1, C, h, 32 * k2, i0, outp);
        __syncthreads();
        if (k2 < 4) stage(32 * k2 + 32, 0);
        compute_chunk<1>(Lr, a0, a1, C, h, 32 * k2 + 16, i0, outp);
        __syncthreads();
        if (k2 < 4) stage(32 * k2 + 48, 1);
    }
}

// ---------------------------------------------------------------------------
// Orchestration.
//   d_out : T0 (un-normalized padded bf16 im_c) -> final output
//   d_ws  : G0, G1 (bf16 padded dual copies), Tn (bf16)  — ~57 MB
// ---------------------------------------------------------------------------
extern "C" void kernel_launch(void* const* d_in, const int* in_sizes, int n_in,
                              void* d_out, int out_size, void* d_ws, size_t ws_size,
                              hipStream_t stream)
{
    const float* im = (const float*)d_in[0];
    const float* tmpl = (const float*)d_in[1];
    float* outp = (float*)d_out;
    __hip_bfloat16* T0 = (__hip_bfloat16*)d_out;
    __hip_bfloat16* G0 = (__hip_bfloat16*)d_ws;
    __hip_bfloat16* G1 = G0 + (size_t)BC * PST;
    __hip_bfloat16* Tn = G1 + (size_t)BC * PST;

    k_template<<<48, 256, 0, stream>>>(tmpl, Tn);
    k_center2<<<dim3(8, 16, BC), 256, 0, stream>>>(im, T0);
    k_norm2<<<dim3(8, 16, BC), 256, 0, stream>>>(T0, G0, G1);
    k_corr_mfma<<<dim3(4, 4, BC), 256, 0, stream>>>(G0, G1, Tn, outp);
}